// Round 4
// baseline (406.477 us; speedup 1.0000x reference)
//
#include <hip/hip_runtime.h>
#include <hip/hip_cooperative_groups.h>

namespace cg = cooperative_groups;

#define HWD 256
#define NB 2
#define NV 5023
#define NF 2048
#define NGRP 8            // face groups = raster segments (f>>8)
#define GRPSZ 256         // faces per group
#define GRID 1024

// ws layout:
//  zk    @ 0x000000  131072 * 8B = 1 MiB
//  frP   @ 0x100000  4096 * 64B  = 256 KiB  (16 floats per face)
//  vattr @ 0x140000  10046*6*4B  = 236 KiB (region 256 KiB)
//  cnt   @ 0x180000  4096 * 4B   = 16 KiB
//  list  @ 0x184000  4096 * 256 * 2B = 2 MiB

__device__ __forceinline__ float pix_coord(int i) {
    return ((float)i + 0.5f) * 0.0078125f - 1.0f;   // exact fp32
}

__global__ __launch_bounds__(256, 4) void k_all(
        const float* __restrict__ verts, const float* __restrict__ tex,
        const float* __restrict__ uv,    const float* __restrict__ tv,
        const int* __restrict__ faces,   float* __restrict__ out,
        unsigned long long* __restrict__ zk, unsigned int* __restrict__ cnt,
        float* __restrict__ frP, float* __restrict__ vattr,
        unsigned short* __restrict__ list) {
    cg::grid_group grid = cg::this_grid();
    int blk = blockIdx.x, tid = threadIdx.x;

    // ---------------- phase 0: init zk/cnt + vertex attrs + face setup ----
    if (blk < 512) {
        int i = blk * 256 + tid;
        zk[i] = (0x407FFFFFull << 32) | 0x80000000ull;   // z=-1.0, "no face"
    } else if (blk < 528) {
        cnt[(blk - 512) * 256 + tid] = 0;
    } else if (blk < 568) {
        int i = (blk - 528) * 256 + tid;
        if (i < NB * NV) {
            int b = i / NV, v = i - b * NV;
            float u = __fmul_rn(uv[2 * v + 0], 255.0f);
            float w = __fmul_rn(uv[2 * v + 1], 255.0f);
            float uf = floorf(u); uf = fminf(fmaxf(uf, 0.0f), 254.0f);
            float vf = floorf(w); vf = fminf(fmaxf(vf, 0.0f), 254.0f);
            int u0 = (int)uf, v0 = (int)vf;
            float fu = __fsub_rn(u, uf);
            float fv = __fsub_rn(w, vf);
            const float* t   = tex + (size_t)b * HWD * HWD * 3;
            const float* c00 = t + ((size_t)v0 * HWD + u0) * 3;
            const float* c01 = c00 + 3;
            const float* c10 = c00 + HWD * 3;
            const float* c11 = c10 + 3;
            float gu = 1.0f - fu, gv = 1.0f - fv;
            float* o = vattr + (size_t)i * 6;
            for (int c = 0; c < 3; ++c) {
                float l0 = c00[c] * gu + c01[c] * fu;
                float l1 = c10[c] * gu + c11[c] * fu;
                o[c] = l0 * gv + l1 * fv;
            }
            const float* vp = verts + ((size_t)b * NV + v) * 3;
            o[3] = vp[0]; o[4] = vp[1]; o[5] = vp[2];
        }
    } else if (blk < 584) {
        int i = (blk - 568) * 256 + tid;
        if (i < NB * NF) {
            int b = i / NF, f = i - b * NF;
            int i0 = faces[3 * f + 0], i1 = faces[3 * f + 1], i2 = faces[3 * f + 2];
            const float* base = tv + (size_t)b * NV * 3;
            float x0 = base[3 * i0 + 0], y0 = base[3 * i0 + 1], z0 = base[3 * i0 + 2];
            float x1 = base[3 * i1 + 0], y1 = base[3 * i1 + 1], z1 = base[3 * i1 + 2];
            float x2 = base[3 * i2 + 0], y2 = base[3 * i2 + 1], z2 = base[3 * i2 + 2];
            float dy12 = __fsub_rn(y1, y2);
            float dx21 = __fsub_rn(x2, x1);
            float dy20 = __fsub_rn(y2, y0);
            float dx02 = __fsub_rn(x0, x2);
            float denom = __fadd_rn(__fmul_rn(dy12, __fsub_rn(x0, x2)),
                                    __fmul_rn(dx21, __fsub_rn(y0, y2)));
            bool valid = fabsf(denom) > 1e-8f;
            int xlo = 1, xhi = 0, ylo = 1, yhi = 0;
            if (valid) {
                if (fabsf(denom) < 1e-3f) {
                    xlo = 0; xhi = 255; ylo = 0; yhi = 255;
                } else {
                    float xmn = fminf(x0, fminf(x1, x2)), xmx = fmaxf(x0, fmaxf(x1, x2));
                    float ymn = fminf(y0, fminf(y1, y2)), ymx = fmaxf(y0, fmaxf(y1, y2));
                    xlo = (int)floorf((xmn + 1.0f) * 128.0f - 0.5f) - 1;
                    xhi = (int)ceilf ((xmx + 1.0f) * 128.0f - 0.5f) + 1;
                    ylo = (int)floorf((ymn + 1.0f) * 128.0f - 0.5f) - 1;
                    yhi = (int)ceilf ((ymx + 1.0f) * 128.0f - 0.5f) + 1;
                    xlo = max(xlo, 0); ylo = max(ylo, 0);
                    xhi = min(xhi, 255); yhi = min(yhi, 255);
                    if (xhi < xlo || yhi < ylo) { xlo = 1; xhi = 0; ylo = 1; yhi = 0; }
                }
            }
            float* o = frP + (size_t)i * 16;
            o[0] = dy12; o[1] = dx21; o[2] = x2; o[3] = y2;
            o[4] = dy20; o[5] = dx02; o[6] = valid ? (1.0f / denom) : 0.0f;
            o[7] = z0; o[8] = z1; o[9] = z2;
            ((unsigned int*)o)[10] = (unsigned)xlo | ((unsigned)xhi << 16);
            ((unsigned int*)o)[11] = (unsigned)ylo | ((unsigned)yhi << 16);
            o[12] = denom;
        }
    }
    grid.sync();

    // ---------------- phase 1: bin (1 wave per face) ----------------------
    {
        int gi = blk * 4 + (tid >> 6);     // 0..4095
        int lane = tid & 63;
        int b = gi >> 11, f = gi & (NF - 1);
        int grp = f >> 8;
        const float* o = frP + (size_t)gi * 16;
        unsigned int bbx = ((const unsigned int*)o)[10];
        unsigned int bby = ((const unsigned int*)o)[11];
        int xlo = (int)(bbx & 0xffffu), xhi = (int)(bbx >> 16);
        int ylo = (int)(bby & 0xffffu), yhi = (int)(bby >> 16);
        if (xhi >= xlo && yhi >= ylo) {
            int txlo = xlo >> 4, txhi = xhi >> 4;
            int tylo = ylo >> 4, tyhi = yhi >> 4;
            int ntx = txhi - txlo + 1, nty = tyhi - tylo + 1;
            int total = ntx * nty;
            float inv = o[6], denom = o[12];
            bool skipTest = fabsf(denom) < 1e-3f;
            float x2 = o[2], y2 = o[3];
            float A0 = o[0] * inv, B0 = o[1] * inv;
            float A1 = o[4] * inv, B1 = o[5] * inv;
            float C  = A0 + A1,    D  = B0 + B1;
            unsigned int baseIdx = (unsigned)(b * NGRP + grp) << 8;
            for (int t = lane; t < total; t += 64) {
                int ty = tylo + t / ntx;
                int tx = txlo + t - (t / ntx) * ntx;
                bool keep = true;
                if (!skipTest) {
                    float x0n = pix_coord(tx * 16), x1n = pix_coord(tx * 16 + 15);
                    float y0n = pix_coord(ty * 16), y1n = pix_coord(ty * 16 + 15);
                    float w0m = A0 * ((A0 > 0.f ? x1n : x0n) - x2) + B0 * ((B0 > 0.f ? y1n : y0n) - y2);
                    float w1m = A1 * ((A1 > 0.f ? x1n : x0n) - x2) + B1 * ((B1 > 0.f ? y1n : y0n) - y2);
                    float w2m = 1.0f - (C * ((C > 0.f ? x0n : x1n) - x2) + D * ((D > 0.f ? y0n : y1n) - y2));
                    const float eps = 0.02f;
                    keep = (w0m >= -eps) && (w1m >= -eps) && (w2m >= -eps);
                }
                if (keep) {
                    unsigned int idx = baseIdx + (unsigned)(ty * 16 + tx);
                    unsigned int slot = atomicAdd(&cnt[idx], 1u);
                    if (slot < GRPSZ) list[((size_t)idx << 8) + slot] = (unsigned short)f;
                }
            }
        }
    }
    grid.sync();

    // ---------------- phase 2: raster (4 tile-segments per block) ---------
    __shared__ float fdat[GRPSZ * 12];
    for (int u = 0; u < 4; ++u) {
        int unit = blk * 4 + u;                 // = ((b*8+seg)<<8) | tile
        int tile = unit & 255;
        int b    = unit >> 11;
        unsigned int count = cnt[unit];
        if (count > GRPSZ) count = GRPSZ;
        const unsigned short* lst = list + ((size_t)unit << 8);
        const float* frB = frP + ((size_t)b * NF) * 16;

        __syncthreads();
        if (count) {
            int n12 = (int)count * 12;
            for (int idx = tid; idx < n12; idx += 256) {
                int face = idx / 12;
                int field = idx - face * 12;
                int gf = lst[face];
                float v;
                if (field < 10)      v = frB[((size_t)gf << 4) + field];
                else if (field == 10) v = __uint_as_float((unsigned)gf);
                else                 v = 0.0f;
                fdat[idx] = v;
            }
        }
        __syncthreads();
        if (count) {
            int px = ((tile & 15) << 4) + (tid & 15);
            int py = ((tile >> 4) << 4) + (tid >> 4);
            float pxf = pix_coord(px), pyf = pix_coord(py);
            unsigned long long best = 0ull;
            #pragma unroll 4
            for (int j = 0; j < (int)count; ++j) {
                const float* fp = &fdat[j * 12];
                float t0 = __fsub_rn(pxf, fp[2]);
                float t1 = __fsub_rn(pyf, fp[3]);
                float w0 = __fmul_rn(__fadd_rn(__fmul_rn(fp[0], t0), __fmul_rn(fp[1], t1)), fp[6]);
                float w1 = __fmul_rn(__fadd_rn(__fmul_rn(fp[4], t0), __fmul_rn(fp[5], t1)), fp[6]);
                float w2 = __fsub_rn(__fsub_rn(1.0f, w0), w1);
                if (w0 >= 0.0f && w1 >= 0.0f && w2 >= 0.0f) {
                    float z = __fadd_rn(__fadd_rn(__fmul_rn(w0, fp[7]), __fmul_rn(w1, fp[8])),
                                        __fmul_rn(w2, fp[9]));
                    unsigned int gf = __float_as_uint(fp[10]);
                    unsigned int ub = __float_as_uint(z);
                    unsigned int hi = ub ^ ((unsigned int)(((int)ub) >> 31) | 0x80000000u);
                    unsigned long long key = ((unsigned long long)hi << 32)
                                           | (unsigned long long)(0x7FFFFFFFu - gf);
                    best = (key > best) ? key : best;
                }
            }
            if (best) {
                int pix = (b << 16) + py * HWD + px;
                unsigned long long cur = zk[pix];
                if (best > cur) atomicMax(&zk[pix], best);
            }
        }
    }
    grid.sync();

    // ---------------- phase 3: shade --------------------------------------
    {
        int i = blk * 256 + tid;
        if (i < NB * HWD * HWD) {
            int b = i >> 16;
            int pix = i & 0xFFFF;
            unsigned long long key = zk[i];
            unsigned int lo = (unsigned int)key;
            unsigned int hi = (unsigned int)(key >> 32);
            float img[6] = {0, 0, 0, 0, 0, 0};
            float alpha, fidf, zout;
            if (lo > 0x7FFFFFFFu) {
                alpha = 0.0f; fidf = -1.0f; zout = -1.0f;
            } else {
                int f = (int)(0x7FFFFFFFu - lo);
                unsigned int zb32 = (hi & 0x80000000u) ? (hi & 0x7FFFFFFFu) : ~hi;
                zout = __uint_as_float(zb32);
                alpha = 1.0f;
                fidf = (float)f;
                const float* fp = frP + ((size_t)(b * NF + f)) * 16;
                int px = pix & 0xFF, py = pix >> 8;
                float t0 = __fsub_rn(pix_coord(px), fp[2]);
                float t1 = __fsub_rn(pix_coord(py), fp[3]);
                float w0 = __fmul_rn(__fadd_rn(__fmul_rn(fp[0], t0), __fmul_rn(fp[1], t1)), fp[6]);
                float w1 = __fmul_rn(__fadd_rn(__fmul_rn(fp[4], t0), __fmul_rn(fp[5], t1)), fp[6]);
                float w2 = __fsub_rn(__fsub_rn(1.0f, w0), w1);
                int i0 = faces[3 * f + 0], i1 = faces[3 * f + 1], i2 = faces[3 * f + 2];
                const float* a0 = vattr + ((size_t)b * NV + i0) * 6;
                const float* a1 = vattr + ((size_t)b * NV + i1) * 6;
                const float* a2 = vattr + ((size_t)b * NV + i2) * 6;
                for (int c = 0; c < 6; ++c)
                    img[c] = __fadd_rn(__fadd_rn(__fmul_rn(w0, a0[c]), __fmul_rn(w1, a1[c])),
                                       __fmul_rn(w2, a2[c]));
            }
            const size_t plane = (size_t)HWD * HWD;
            for (int c = 0; c < 6; ++c)
                out[((size_t)b * 6 + c) * plane + pix] = img[c];
            out[786432 + i]  = alpha;
            out[917504 + i]  = fidf;
            out[1048576 + i] = zout;
        }
    }
}

extern "C" void kernel_launch(void* const* d_in, const int* in_sizes, int n_in,
                              void* d_out, int out_size, void* d_ws, size_t ws_size,
                              hipStream_t stream) {
    (void)in_sizes; (void)n_in; (void)out_size; (void)ws_size;
    const float* verts = (const float*)d_in[0];
    const float* tv    = (const float*)d_in[1];
    const float* tex   = (const float*)d_in[2];
    const float* uv    = (const float*)d_in[3];
    const int*   faces = (const int*)d_in[4];
    float* out = (float*)d_out;

    char* ws = (char*)d_ws;
    unsigned long long* zk    = (unsigned long long*)ws;            // 1 MiB
    float*              frP   = (float*)(ws + 0x100000);            // 256 KiB
    float*              vattr = (float*)(ws + 0x140000);            // 256 KiB
    unsigned int*       cnt   = (unsigned int*)(ws + 0x180000);     // 16 KiB
    unsigned short*     list  = (unsigned short*)(ws + 0x184000);   // 2 MiB

    void* args[] = { (void*)&verts, (void*)&tex, (void*)&uv, (void*)&tv,
                     (void*)&faces, (void*)&out, (void*)&zk, (void*)&cnt,
                     (void*)&frP, (void*)&vattr, (void*)&list };
    hipLaunchCooperativeKernel((void*)k_all, dim3(GRID), dim3(256), args, 0, stream);
}

// Round 5
// 177.986 us; speedup vs baseline: 2.2838x; 2.2838x over previous
//
#include <hip/hip_runtime.h>

#define HWD 256
#define NB 2
#define NV 5023
#define NF 2048

// ws layout:
//  zk         @ 0x000000  131072 * 8B = 1 MiB     (raster plain-stores all; no init)
//  frP        @ 0x100000  4096 * 64B  = 256 KiB   (16 floats per face)
//  vattr      @ 0x140000  10046*6*4B  = 236 KiB   (region 256 KiB)
//  fidSorted  @ 0x180000  4096 * 2B   = 8 KiB
//  zmaxSorted @ 0x182000  4096 * 4B   = 16 KiB
//  binData    @ 0x186000  4096 * 48B  = 192 KiB
//  list       @ 0x1B6000  512 * 2048 * 2B = 2 MiB
//  listCnt    @ 0x3B6000  512 * 4B

__device__ __forceinline__ float pix_coord(int i) {
    return ((float)i + 0.5f) * 0.0078125f - 1.0f;   // exact fp32
}

// frP fields: 0 dy12, 1 dx21, 2 x2, 3 y2, 4 dy20, 5 dx02, 6 inv, 7 z0, 8 z1, 9 z2,
//             10 bbx, 11 bby, 12 denom, 13 zmax
__global__ __launch_bounds__(256) void k_prep(const float* __restrict__ verts,
                                              const float* __restrict__ tex,
                                              const float* __restrict__ uv,
                                              const float* __restrict__ tv,
                                              const int* __restrict__ faces,
                                              float* __restrict__ frP,
                                              float* __restrict__ vattr) {
    int blk = blockIdx.x, tid = threadIdx.x;
    if (blk < 40) {                       // ---- per-vertex attributes ----
        int i = blk * 256 + tid;
        if (i >= NB * NV) return;
        int b = i / NV, v = i - b * NV;
        float u = __fmul_rn(uv[2 * v + 0], 255.0f);
        float w = __fmul_rn(uv[2 * v + 1], 255.0f);
        float uf = floorf(u); uf = fminf(fmaxf(uf, 0.0f), 254.0f);
        float vf = floorf(w); vf = fminf(fmaxf(vf, 0.0f), 254.0f);
        int u0 = (int)uf, v0 = (int)vf;
        float fu = __fsub_rn(u, uf);
        float fv = __fsub_rn(w, vf);
        const float* t   = tex + (size_t)b * HWD * HWD * 3;
        const float* c00 = t + ((size_t)v0 * HWD + u0) * 3;
        const float* c01 = c00 + 3;
        const float* c10 = c00 + HWD * 3;
        const float* c11 = c10 + 3;
        float gu = 1.0f - fu, gv = 1.0f - fv;
        float* o = vattr + (size_t)i * 6;
        for (int c = 0; c < 3; ++c) {
            float l0 = c00[c] * gu + c01[c] * fu;
            float l1 = c10[c] * gu + c11[c] * fu;
            o[c] = l0 * gv + l1 * fv;
        }
        const float* vp = verts + ((size_t)b * NV + v) * 3;
        o[3] = vp[0]; o[4] = vp[1]; o[5] = vp[2];
        return;
    }
    // ---- per-face setup ----
    int i = (blk - 40) * 256 + tid;
    if (i >= NB * NF) return;
    int b = i / NF, f = i - b * NF;
    int i0 = faces[3 * f + 0], i1 = faces[3 * f + 1], i2 = faces[3 * f + 2];
    const float* base = tv + (size_t)b * NV * 3;
    float x0 = base[3 * i0 + 0], y0 = base[3 * i0 + 1], z0 = base[3 * i0 + 2];
    float x1 = base[3 * i1 + 0], y1 = base[3 * i1 + 1], z1 = base[3 * i1 + 2];
    float x2 = base[3 * i2 + 0], y2 = base[3 * i2 + 1], z2 = base[3 * i2 + 2];

    float dy12 = __fsub_rn(y1, y2);
    float dx21 = __fsub_rn(x2, x1);
    float dy20 = __fsub_rn(y2, y0);
    float dx02 = __fsub_rn(x0, x2);
    float denom = __fadd_rn(__fmul_rn(dy12, __fsub_rn(x0, x2)),
                            __fmul_rn(dx21, __fsub_rn(y0, y2)));
    bool valid = fabsf(denom) > 1e-8f;

    int xlo = 1, xhi = 0, ylo = 1, yhi = 0;
    if (valid) {
        if (fabsf(denom) < 1e-3f) {
            xlo = 0; xhi = 255; ylo = 0; yhi = 255;
        } else {
            float xmn = fminf(x0, fminf(x1, x2)), xmx = fmaxf(x0, fmaxf(x1, x2));
            float ymn = fminf(y0, fminf(y1, y2)), ymx = fmaxf(y0, fmaxf(y1, y2));
            xlo = (int)floorf((xmn + 1.0f) * 128.0f - 0.5f) - 1;
            xhi = (int)ceilf ((xmx + 1.0f) * 128.0f - 0.5f) + 1;
            ylo = (int)floorf((ymn + 1.0f) * 128.0f - 0.5f) - 1;
            yhi = (int)ceilf ((ymx + 1.0f) * 128.0f - 0.5f) + 1;
            xlo = max(xlo, 0); ylo = max(ylo, 0);
            xhi = min(xhi, 255); yhi = min(yhi, 255);
            if (xhi < xlo || yhi < ylo) { xlo = 1; xhi = 0; ylo = 1; yhi = 0; }
        }
    }
    float* o = frP + (size_t)i * 16;
    o[0] = dy12; o[1] = dx21; o[2] = x2; o[3] = y2;
    o[4] = dy20; o[5] = dx02; o[6] = valid ? (1.0f / denom) : 0.0f;
    o[7] = z0; o[8] = z1; o[9] = z2;
    ((unsigned int*)o)[10] = (unsigned)xlo | ((unsigned)xhi << 16);
    ((unsigned int*)o)[11] = (unsigned)ylo | ((unsigned)yhi << 16);
    o[12] = denom;
    o[13] = valid ? fmaxf(z0, fmaxf(z1, z2)) : -2.0f;
}

// sort faces by zmax descending (bitonic, per batch); emit rank-indexed arrays
__global__ __launch_bounds__(1024) void k_sort(const float* __restrict__ frP,
                                               unsigned short* __restrict__ fidSorted,
                                               float* __restrict__ zmaxSorted,
                                               float* __restrict__ binData) {
    int b = blockIdx.x, tid = threadIdx.x;
    __shared__ unsigned long long key[NF];
    for (int i = tid; i < NF; i += 1024) {
        float zmax = frP[(((size_t)(b * NF + i)) << 4) + 13];
        unsigned int ub = __float_as_uint(zmax);
        unsigned int zo = (ub & 0x80000000u) ? ~ub : (ub | 0x80000000u);
        key[i] = ((unsigned long long)zo << 16) | (unsigned)i;
    }
    __syncthreads();
    for (int k = 2; k <= NF; k <<= 1) {
        for (int j = k >> 1; j > 0; j >>= 1) {
            for (int i = tid; i < NF; i += 1024) {
                int ixj = i ^ j;
                if (ixj > i) {
                    unsigned long long a = key[i], c = key[ixj];
                    bool sw = ((i & k) == 0) ? (a < c) : (a > c);   // descending
                    if (sw) { key[i] = c; key[ixj] = a; }
                }
            }
            __syncthreads();
        }
    }
    for (int r = tid; r < NF; r += 1024) {
        int fid = (int)(key[r] & 0xFFFFu);
        fidSorted[b * NF + r] = (unsigned short)fid;
        const float* o = frP + (((size_t)(b * NF + fid)) << 4);
        zmaxSorted[b * NF + r] = o[13];
        float inv = o[6];
        float A0 = o[0] * inv, B0 = o[1] * inv;
        float A1 = o[4] * inv, B1 = o[5] * inv;
        float* bd = binData + (size_t)(b * NF + r) * 12;
        bd[0] = o[10]; bd[1] = o[11];
        bd[2] = A0; bd[3] = B0; bd[4] = A1; bd[5] = B1;
        bd[6] = A0 + A1; bd[7] = B0 + B1;
        bd[8] = o[2]; bd[9] = o[3];
        bd[10] = (fabsf(o[12]) < 1e-3f) ? 1.0f : 0.0f;
        bd[11] = 0.0f;
    }
}

// one wave per (b,tile): scan sorted ranks, ballot-compact keepers (ordered, no atomics)
__global__ __launch_bounds__(64) void k_bin(const float* __restrict__ binData,
                                            unsigned short* __restrict__ list,
                                            unsigned int* __restrict__ listCnt) {
    int bt = blockIdx.x;
    int b = bt >> 8, tile = bt & 255;
    int lane = threadIdx.x;
    int tlx = tile & 15, tly = tile >> 4;
    float x0n = pix_coord(tlx * 16), x1n = pix_coord(tlx * 16 + 15);
    float y0n = pix_coord(tly * 16), y1n = pix_coord(tly * 16 + 15);
    unsigned int cnt = 0;
    unsigned short* lst = list + (size_t)bt * NF;
    for (int r = lane; r < NF; r += 64) {
        const float* bd = binData + (size_t)(b * NF + r) * 12;
        unsigned int bbx = __float_as_uint(bd[0]), bby = __float_as_uint(bd[1]);
        int xlo = (int)(bbx & 0xffffu), xhi = (int)(bbx >> 16);
        int ylo = (int)(bby & 0xffffu), yhi = (int)(bby >> 16);
        bool keep = (xhi >= xlo) && (tlx >= (xlo >> 4)) && (tlx <= (xhi >> 4))
                                 && (tly >= (ylo >> 4)) && (tly <= (yhi >> 4));
        if (keep && bd[10] == 0.0f) {
            float A0 = bd[2], B0 = bd[3], A1 = bd[4], B1 = bd[5];
            float C = bd[6], D = bd[7], x2 = bd[8], y2 = bd[9];
            float w0m = A0 * ((A0 > 0.f ? x1n : x0n) - x2) + B0 * ((B0 > 0.f ? y1n : y0n) - y2);
            float w1m = A1 * ((A1 > 0.f ? x1n : x0n) - x2) + B1 * ((B1 > 0.f ? y1n : y0n) - y2);
            float w2m = 1.0f - (C * ((C > 0.f ? x0n : x1n) - x2) + D * ((D > 0.f ? y0n : y1n) - y2));
            keep = (w0m >= -0.02f) && (w1m >= -0.02f) && (w2m >= -0.02f);
        }
        unsigned long long mask = __ballot(keep);
        if (keep) {
            int pos = cnt + __popcll(mask & ((1ull << lane) - 1ull));
            lst[pos] = (unsigned short)r;
        }
        cnt += __popcll(mask);
    }
    if (lane == 0) listCnt[bt] = cnt;
}

// one block per (b,tile): iterate rank-sorted list, early-z break, plain store
__global__ __launch_bounds__(256) void k_raster(const float* __restrict__ frP,
                                                const unsigned short* __restrict__ fidSorted,
                                                const float* __restrict__ zmaxSorted,
                                                const unsigned short* __restrict__ list,
                                                const unsigned int* __restrict__ listCnt,
                                                unsigned long long* __restrict__ zk) {
    int bt = blockIdx.x;
    int b = bt >> 8, tile = bt & 255;
    int tid = threadIdx.x;
    unsigned int count = listCnt[bt];
    int px = ((tile & 15) << 4) + (tid & 15);
    int py = ((tile >> 4) << 4) + (tid >> 4);
    float pxf = pix_coord(px), pyf = pix_coord(py);
    const unsigned short* lst = list + (size_t)bt * NF;
    const float* frB = frP + (((size_t)b * NF) << 4);
    const unsigned short* fS = fidSorted + b * NF;
    const float* zS = zmaxSorted + b * NF;

    __shared__ float fdat[64 * 12];
    __shared__ float red[4];
    unsigned long long best = 0ull;
    float curz = -1.0f, tile_min = -1.0f;

    for (unsigned int c = 0; c < count; c += 64) {
        int r0 = lst[c];
        if (zS[r0] < tile_min - 1e-5f) break;   // all remaining faces have zmax <= this
        int n = min(64u, count - c);
        __syncthreads();
        for (int idx = tid; idx < n * 12; idx += 256) {
            int face = idx / 12;
            int field = idx - face * 12;
            int fid = fS[lst[c + face]];
            float v;
            if (field < 10)       v = frB[((size_t)fid << 4) + field];
            else if (field == 10) v = __uint_as_float((unsigned)fid);
            else                  v = 0.0f;
            fdat[idx] = v;
        }
        __syncthreads();
        for (int j = 0; j < n; ++j) {
            const float* fp = &fdat[j * 12];
            float t0 = __fsub_rn(pxf, fp[2]);
            float t1 = __fsub_rn(pyf, fp[3]);
            float w0 = __fmul_rn(__fadd_rn(__fmul_rn(fp[0], t0), __fmul_rn(fp[1], t1)), fp[6]);
            float w1 = __fmul_rn(__fadd_rn(__fmul_rn(fp[4], t0), __fmul_rn(fp[5], t1)), fp[6]);
            float w2 = __fsub_rn(__fsub_rn(1.0f, w0), w1);
            if (w0 >= 0.0f && w1 >= 0.0f && w2 >= 0.0f) {
                float z = __fadd_rn(__fadd_rn(__fmul_rn(w0, fp[7]), __fmul_rn(w1, fp[8])),
                                    __fmul_rn(w2, fp[9]));
                unsigned int gf = __float_as_uint(fp[10]);
                unsigned int ub = __float_as_uint(z);
                unsigned int hi = ub ^ ((unsigned int)(((int)ub) >> 31) | 0x80000000u);
                unsigned long long key = ((unsigned long long)hi << 32)
                                       | (unsigned long long)(0x7FFFFFFFu - gf);
                if (key > best) { best = key; curz = z; }
            }
        }
        float wmin = curz;
        for (int off = 32; off; off >>= 1) wmin = fminf(wmin, __shfl_down(wmin, off));
        if ((tid & 63) == 0) red[tid >> 6] = wmin;
        __syncthreads();
        tile_min = fminf(fminf(red[0], red[1]), fminf(red[2], red[3]));
    }

    const unsigned long long EMPTY = (0x407FFFFFull << 32) | 0x80000000ull;
    zk[(b << 16) + py * HWD + px] = best ? best : EMPTY;
}

__global__ __launch_bounds__(256) void k_shade(const unsigned long long* __restrict__ zk,
                                               const float* __restrict__ frP,
                                               const int* __restrict__ faces,
                                               const float* __restrict__ vattr,
                                               float* __restrict__ out) {
    int i = blockIdx.x * 256 + threadIdx.x;
    int b = i >> 16;
    int pix = i & 0xFFFF;
    unsigned long long key = zk[i];
    unsigned int lo = (unsigned int)key;
    unsigned int hi = (unsigned int)(key >> 32);

    float img[6] = {0, 0, 0, 0, 0, 0};
    float alpha, fidf, zout;
    if (lo > 0x7FFFFFFFu) {
        alpha = 0.0f; fidf = -1.0f; zout = -1.0f;
    } else {
        int f = (int)(0x7FFFFFFFu - lo);
        unsigned int zb32 = (hi & 0x80000000u) ? (hi & 0x7FFFFFFFu) : ~hi;
        zout = __uint_as_float(zb32);
        alpha = 1.0f;
        fidf = (float)f;
        const float* fp = frP + ((size_t)(b * NF + f)) * 16;
        int px = pix & 0xFF, py = pix >> 8;
        float t0 = __fsub_rn(pix_coord(px), fp[2]);
        float t1 = __fsub_rn(pix_coord(py), fp[3]);
        float w0 = __fmul_rn(__fadd_rn(__fmul_rn(fp[0], t0), __fmul_rn(fp[1], t1)), fp[6]);
        float w1 = __fmul_rn(__fadd_rn(__fmul_rn(fp[4], t0), __fmul_rn(fp[5], t1)), fp[6]);
        float w2 = __fsub_rn(__fsub_rn(1.0f, w0), w1);
        int i0 = faces[3 * f + 0], i1 = faces[3 * f + 1], i2 = faces[3 * f + 2];
        const float* a0 = vattr + ((size_t)b * NV + i0) * 6;
        const float* a1 = vattr + ((size_t)b * NV + i1) * 6;
        const float* a2 = vattr + ((size_t)b * NV + i2) * 6;
        for (int c = 0; c < 6; ++c)
            img[c] = __fadd_rn(__fadd_rn(__fmul_rn(w0, a0[c]), __fmul_rn(w1, a1[c])),
                               __fmul_rn(w2, a2[c]));
    }

    const size_t plane = (size_t)HWD * HWD;
    for (int c = 0; c < 6; ++c)
        out[((size_t)b * 6 + c) * plane + pix] = img[c];
    out[786432 + i]  = alpha;
    out[917504 + i]  = fidf;
    out[1048576 + i] = zout;
}

extern "C" void kernel_launch(void* const* d_in, const int* in_sizes, int n_in,
                              void* d_out, int out_size, void* d_ws, size_t ws_size,
                              hipStream_t stream) {
    (void)in_sizes; (void)n_in; (void)out_size; (void)ws_size;
    const float* verts = (const float*)d_in[0];
    const float* tv    = (const float*)d_in[1];
    const float* tex   = (const float*)d_in[2];
    const float* uv    = (const float*)d_in[3];
    const int*   faces = (const int*)d_in[4];
    float* out = (float*)d_out;

    char* ws = (char*)d_ws;
    unsigned long long* zk      = (unsigned long long*)ws;             // 1 MiB
    float*              frP     = (float*)(ws + 0x100000);             // 256 KiB
    float*              vattr   = (float*)(ws + 0x140000);             // 256 KiB
    unsigned short*     fidS    = (unsigned short*)(ws + 0x180000);    // 8 KiB
    float*              zmaxS   = (float*)(ws + 0x182000);             // 16 KiB
    float*              binData = (float*)(ws + 0x186000);             // 192 KiB
    unsigned short*     list    = (unsigned short*)(ws + 0x1B6000);    // 2 MiB
    unsigned int*       listCnt = (unsigned int*)(ws + 0x3B6000);      // 2 KiB

    k_prep  <<<56, 256, 0, stream>>>(verts, tex, uv, tv, faces, frP, vattr);
    k_sort  <<<NB, 1024, 0, stream>>>(frP, fidS, zmaxS, binData);
    k_bin   <<<512, 64, 0, stream>>>(binData, list, listCnt);
    k_raster<<<512, 256, 0, stream>>>(frP, fidS, zmaxS, list, listCnt, zk);
    k_shade <<<512, 256, 0, stream>>>(zk, frP, faces, vattr, out);
}